// Round 2
// baseline (211.317 us; speedup 1.0000x reference)
//
#include <hip/hip_runtime.h>
#include <hip/hip_bf16.h>

#define NN     270
#define MPAD   320
#define NFEAT  4096
#define NHID   1024
#define NHEADS 8
#define NCLS   8
#define NDRUG  175
#define NMIC   95
#define LALPHA 0.2f

typedef unsigned short u16;
typedef unsigned int   u32;
typedef __attribute__((ext_vector_type(8))) short bf16x8;
typedef __attribute__((ext_vector_type(4))) short bf16x4;
typedef __attribute__((ext_vector_type(4))) float f32x4;

static __device__ __forceinline__ u16 f2bf(float f) {
  union { float f; u32 u; } v; v.f = f;
  u32 r = v.u + 0x7FFFu + ((v.u >> 16) & 1u);   // round-to-nearest-even
  return (u16)(r >> 16);
}
static __device__ __forceinline__ float bf2f(u16 b) {
  union { u32 u; float f; } v; v.u = ((u32)b) << 16;
  return v.f;
}
static __device__ __forceinline__ float wave_red(float v) {
  #pragma unroll
  for (int o = 32; o > 0; o >>= 1) v += __shfl_down(v, o, 64);
  return v;
}

// ---------------- K0: x (f32) -> xb (bf16), zero-padded to 320 rows ----------
__global__ void cvt_x(const float* __restrict__ x, u16* __restrict__ xb) {
  int i = (blockIdx.x * 256 + threadIdx.x) * 8;
  if (i >= MPAD * NFEAT) return;
  int row = i >> 12;                 // / NFEAT
  uint4 o = {0, 0, 0, 0};
  if (row < NN) {
    float4 a = *(const float4*)(x + i);
    float4 b = *(const float4*)(x + i + 4);
    o.x = (u32)f2bf(a.x) | ((u32)f2bf(a.y) << 16);
    o.y = (u32)f2bf(a.z) | ((u32)f2bf(a.w) << 16);
    o.z = (u32)f2bf(b.x) | ((u32)f2bf(b.y) << 16);
    o.w = (u32)f2bf(b.z) | ((u32)f2bf(b.w) << 16);
  }
  *(uint4*)(xb + i) = o;
}

// ---------------- K1: H = x @ W  (per head), bf16 MFMA ----------------
// 1024 threads = 16 waves: (ksg 0..1) x (wm 0..3 -> 80-row band) x (wn 0..1 -> 16 cols).
// Each ksg half accumulates K=2048 in regs; LDS f32 reduce at the end.
// A-frags read directly from xb (L2-resident, contiguous bf16x8); only W staged
// in LDS (double-buffered, f32->bf16 transposed), prefetched one iter ahead.
__global__ __launch_bounds__(1024, 4) void gemm1(const u16* __restrict__ xb,
                                                 const float* __restrict__ W,
                                                 float* __restrict__ H,
                                                 u16* __restrict__ Hb) {
  __shared__ __align__(16) u16 lB[2][2][32 * 72];   // [ksg][dbuf][col][k] stride 72
  __shared__ __align__(16) float red[MPAD * 32];    // cross-ksg reduce
  const int tid  = threadIdx.x;
  const int lane = tid & 63;
  const int wid  = tid >> 6;
  const int ksg  = wid >> 3;       // k-half
  const int wm   = (wid >> 1) & 3; // 80-row band
  const int wn   = wid & 1;        // 16-col band
  const int c0   = blockIdx.x * 32;
  const int headB = c0 >> 10;
  const int jB    = c0 & 1023;
  const int gtid = tid & 511;
  const int kk   = gtid >> 3;        // 0..63
  const int jc   = (gtid & 7) << 2;  // 0,4,..,28
  const int colB = wn * 16 + (lane & 15);

  const float* wp = W + (size_t)headB * NFEAT * NHID
                      + (size_t)(ksg * 2048 + kk) * NHID + jB + jc;
  float4 wv = *(const float4*)wp;
  wp += 64 * NHID;

  f32x4 acc[5];
  #pragma unroll
  for (int m = 0; m < 5; ++m) acc[m] = (f32x4){0.f, 0.f, 0.f, 0.f};

  int cur = 0;
  for (int it = 0; it < 32; ++it) {
    // stage current W tile (held in regs) into LDS, transposed to [col][k]
    u16* db = &lB[ksg][cur][0];
    db[(jc + 0) * 72 + kk] = f2bf(wv.x);
    db[(jc + 1) * 72 + kk] = f2bf(wv.y);
    db[(jc + 2) * 72 + kk] = f2bf(wv.z);
    db[(jc + 3) * 72 + kk] = f2bf(wv.w);
    if (it != 31) {                 // prefetch next tile; stays in flight across barrier+MFMA
      wv = *(const float4*)wp;
      wp += 64 * NHID;
    }
    __syncthreads();
    const int kbase = ksg * 2048 + it * 64;
    #pragma unroll
    for (int sub = 0; sub < 2; ++sub) {
      const int ko = sub * 32 + ((lane >> 4) << 3);
      bf16x8 bfrag = *(const bf16x8*)(&lB[ksg][cur][colB * 72 + ko]);
      #pragma unroll
      for (int m = 0; m < 5; ++m) {
        const int row = wm * 80 + m * 16 + (lane & 15);
        bf16x8 afrag = *(const bf16x8*)(xb + (size_t)row * NFEAT + kbase + ko);
        acc[m] = __builtin_amdgcn_mfma_f32_16x16x32_bf16(afrag, bfrag, acc[m], 0, 0, 0);
      }
    }
    cur ^= 1;
  }

  // reduce the two k-halves through LDS, then write H (f32) + Hb (bf16)
  __syncthreads();
  if (ksg == 1) {
    #pragma unroll
    for (int m = 0; m < 5; ++m)
      #pragma unroll
      for (int r = 0; r < 4; ++r) {
        int row = wm * 80 + m * 16 + ((lane >> 4) << 2) + r;
        red[row * 32 + colB] = acc[m][r];
      }
  }
  __syncthreads();
  if (ksg == 0) {
    #pragma unroll
    for (int m = 0; m < 5; ++m)
      #pragma unroll
      for (int r = 0; r < 4; ++r) {
        int row = wm * 80 + m * 16 + ((lane >> 4) << 2) + r;
        if (row < NN) {
          float v = acc[m][r] + red[row * 32 + colB];
          size_t off = ((size_t)headB * NN + row) * NHID + jB + colB;
          H[off]  = v;
          Hb[off] = f2bf(v);
        }
      }
  }
}

// ---------------- K2: src/dst = H @ a_src / a_dst ----------------
__global__ void srcdst(const float* __restrict__ H, const float* __restrict__ a_src,
                       const float* __restrict__ a_dst, float* __restrict__ srcv,
                       float* __restrict__ dstv) {
  const int i = blockIdx.x, h = blockIdx.y;
  const float* hr = H + ((size_t)h * NN + i) * NHID;
  const float* as = a_src + h * NHID;
  const float* ad = a_dst + h * NHID;
  float s = 0.f, d = 0.f;
  for (int j = threadIdx.x; j < NHID; j += 256) {
    float v = hr[j];
    s += v * as[j];
    d += v * ad[j];
  }
  s = wave_red(s); d = wave_red(d);
  __shared__ float rb[8];
  const int lane = threadIdx.x & 63, wid = threadIdx.x >> 6;
  if (lane == 0) { rb[wid] = s; rb[4 + wid] = d; }
  __syncthreads();
  if (threadIdx.x == 0) {
    srcv[h * NN + i] = rb[0] + rb[1] + rb[2] + rb[3];
    dstv[h * NN + i] = rb[4] + rb[5] + rb[6] + rb[7];
  }
}

// ---------------- K3a: e = exp(-leakyrelu(src_i+dst_j))*mask, rowsum ----------------
__global__ void ekern(const int* __restrict__ adj, const float* __restrict__ srcv,
                      const float* __restrict__ dstv, u16* __restrict__ eb,
                      float* __restrict__ rowsum) {
  const int i = blockIdx.x, h = blockIdx.y;
  const int n = threadIdx.x;          // 0..319
  float ev = 0.f;
  if (n < NN && adj[i * NN + n] != 0) {
    float lg = srcv[h * NN + i] + dstv[h * NN + n];
    float lr = lg > 0.f ? lg : LALPHA * lg;
    ev = expf(-lr);
  }
  u16 evb = f2bf(ev);
  eb[(size_t)h * NN * 320 + (size_t)i * 320 + n] = evb;
  float evr = wave_red(bf2f(evb));    // sum the bf16-rounded weights (consistency)
  __shared__ float rb[5];
  const int lane = threadIdx.x & 63, wid = threadIdx.x >> 6;
  if (lane == 0) rb[wid] = evr;
  __syncthreads();
  if (threadIdx.x == 0) rowsum[h * NN + i] = rb[0] + rb[1] + rb[2] + rb[3] + rb[4];
}

// ---------------- K3b: h2 = elu((e @ H) / rowsum), concat heads ----------------
__global__ __launch_bounds__(512) void gemm2(const u16* __restrict__ eb,
                                             const u16* __restrict__ Hb,
                                             const float* __restrict__ rowsum,
                                             float* __restrict__ h2) {
  __shared__ __align__(16) u16 lA[320 * 72];
  __shared__ __align__(16) u16 lB[32 * 72];
  const int tid  = threadIdx.x;
  const int lane = tid & 63;
  const int wid  = tid >> 6;
  const int wm   = wid >> 1;
  const int wn   = wid & 1;
  const int head = blockIdx.x >> 5;
  const int j0   = (blockIdx.x & 31) * 32;
  f32x4 acc[5];
  #pragma unroll
  for (int m = 0; m < 5; ++m) acc[m] = (f32x4){0.f, 0.f, 0.f, 0.f};

  for (int k0 = 0; k0 < 320; k0 += 64) {
    __syncthreads();
    #pragma unroll
    for (int it = 0; it < 5; ++it) {
      int f   = tid + it * 512;
      int row = f >> 3;
      int kc  = (f & 7) << 3;
      bf16x8 v = {0,0,0,0,0,0,0,0};
      if (row < NN) v = *(const bf16x8*)(eb + (size_t)head * NN * 320 + (size_t)row * 320 + k0 + kc);
      *(bf16x8*)(lA + row * 72 + kc) = v;
    }
    {
      int kk2 = tid >> 3;
      int jc2 = (tid & 7) << 2;
      int k   = k0 + kk2;
      u16 v0 = 0, v1 = 0, v2 = 0, v3 = 0;
      if (k < NN) {
        bf16x4 hv = *(const bf16x4*)(Hb + (size_t)head * NN * NHID + (size_t)k * NHID + j0 + jc2);
        v0 = (u16)hv[0]; v1 = (u16)hv[1]; v2 = (u16)hv[2]; v3 = (u16)hv[3];
      }
      lB[(jc2 + 0) * 72 + kk2] = v0;
      lB[(jc2 + 1) * 72 + kk2] = v1;
      lB[(jc2 + 2) * 72 + kk2] = v2;
      lB[(jc2 + 3) * 72 + kk2] = v3;
    }
    __syncthreads();
    #pragma unroll
    for (int sub = 0; sub < 2; ++sub) {
      int ks = sub * 32 + ((lane >> 4) << 3);
      bf16x8 bfrag = *(const bf16x8*)(lB + (wn * 16 + (lane & 15)) * 72 + ks);
      #pragma unroll
      for (int m = 0; m < 5; ++m) {
        int row = wm * 80 + m * 16 + (lane & 15);
        bf16x8 afrag = *(const bf16x8*)(lA + row * 72 + ks);
        acc[m] = __builtin_amdgcn_mfma_f32_16x16x32_bf16(afrag, bfrag, acc[m], 0, 0, 0);
      }
    }
  }
  const int jj = j0 + wn * 16 + (lane & 15);
  #pragma unroll
  for (int m = 0; m < 5; ++m) {
    #pragma unroll
    for (int r = 0; r < 4; ++r) {
      int row = wm * 80 + m * 16 + ((lane >> 4) << 2) + r;
      if (row < NN) {
        float v = acc[m][r] / rowsum[head * NN + row];
        v = v > 0.f ? v : expm1f(v);                 // elu
        h2[(size_t)row * (NHEADS * NHID) + head * NHID + jj] = v;
      }
    }
  }
}

// ---------------- K4: layer-2 h = h2 @ W_out, plus src2/dst2 ----------------
__global__ void layer2(const float* __restrict__ h2, const float* __restrict__ Wout,
                       const float* __restrict__ aos, const float* __restrict__ aod,
                       float* __restrict__ hL2, float* __restrict__ src2,
                       float* __restrict__ dst2) {
  const int i = blockIdx.x;
  float acc[8] = {0,0,0,0,0,0,0,0};
  for (int k = threadIdx.x; k < NHEADS * NHID; k += 256) {
    float hv = h2[(size_t)i * (NHEADS * NHID) + k];
    const float4 w0 = *(const float4*)(Wout + (size_t)k * 8);
    const float4 w1 = *(const float4*)(Wout + (size_t)k * 8 + 4);
    acc[0] += hv * w0.x; acc[1] += hv * w0.y; acc[2] += hv * w0.z; acc[3] += hv * w0.w;
    acc[4] += hv * w1.x; acc[5] += hv * w1.y; acc[6] += hv * w1.z; acc[7] += hv * w1.w;
  }
  #pragma unroll
  for (int c = 0; c < 8; ++c) acc[c] = wave_red(acc[c]);
  __shared__ float rb[4][8];
  const int lane = threadIdx.x & 63, wid = threadIdx.x >> 6;
  if (lane == 0) {
    #pragma unroll
    for (int c = 0; c < 8; ++c) rb[wid][c] = acc[c];
  }
  __syncthreads();
  if (threadIdx.x == 0) {
    float s = 0.f, d = 0.f;
    #pragma unroll
    for (int c = 0; c < 8; ++c) {
      float v = rb[0][c] + rb[1][c] + rb[2][c] + rb[3][c];
      hL2[i * 8 + c] = v;
      s += v * aos[c];
      d += v * aod[c];
    }
    src2[i] = s; dst2[i] = d;
  }
}

// ---------------- K5a: layer-2 attention + aggregation + elu ----------------
__global__ void out2k(const int* __restrict__ adj, const float* __restrict__ src2,
                      const float* __restrict__ dst2, const float* __restrict__ hL2,
                      float* __restrict__ out2) {
  const int i = blockIdx.x;
  float se = 0.f, acc[8] = {0,0,0,0,0,0,0,0};
  for (int n = threadIdx.x; n < NN; n += 256) {
    if (adj[i * NN + n] != 0) {
      float lg = src2[i] + dst2[n];
      float lr = lg > 0.f ? lg : LALPHA * lg;
      float ev = expf(-lr);
      se += ev;
      #pragma unroll
      for (int c = 0; c < 8; ++c) acc[c] += ev * hL2[n * 8 + c];
    }
  }
  se = wave_red(se);
  #pragma unroll
  for (int c = 0; c < 8; ++c) acc[c] = wave_red(acc[c]);
  __shared__ float rb[4][9];
  const int lane = threadIdx.x & 63, wid = threadIdx.x >> 6;
  if (lane == 0) {
    #pragma unroll
    for (int c = 0; c < 8; ++c) rb[wid][c] = acc[c];
    rb[wid][8] = se;
  }
  __syncthreads();
  if (threadIdx.x == 0) {
    float s = rb[0][8] + rb[1][8] + rb[2][8] + rb[3][8];
    #pragma unroll
    for (int c = 0; c < 8; ++c) {
      float v = (rb[0][c] + rb[1][c] + rb[2][c] + rb[3][c]) / s;
      out2[i * 8 + c] = v > 0.f ? v : expm1f(v);
    }
  }
}

// ---------------- K5b: out = drug @ alpha1 @ mic^T ----------------
__global__ void finalk(const float* __restrict__ out2, const float* __restrict__ alpha1,
                       float* __restrict__ out) {
  int t = blockIdx.x * 256 + threadIdx.x;
  if (t >= NDRUG * NMIC) return;
  int d = t / NMIC, m = t % NMIC;
  const float* dr = out2 + d * 8;
  const float* mi = out2 + (NDRUG + m) * 8;
  float r = 0.f;
  #pragma unroll
  for (int c2 = 0; c2 < 8; ++c2) {
    float a = 0.f;
    #pragma unroll
    for (int c1 = 0; c1 < 8; ++c1) a += dr[c1] * alpha1[c1 * 8 + c2];
    r += a * mi[c2];
  }
  out[t] = r;
}

extern "C" void kernel_launch(void* const* d_in, const int* in_sizes, int n_in,
                              void* d_out, int out_size, void* d_ws, size_t ws_size,
                              hipStream_t stream) {
  const float* x      = (const float*)d_in[0];
  const int*   adj    = (const int*)d_in[1];
  const float* W      = (const float*)d_in[2];
  const float* a_src  = (const float*)d_in[3];
  const float* a_dst  = (const float*)d_in[4];
  const float* W_out  = (const float*)d_in[5];
  const float* aos    = (const float*)d_in[6];
  const float* aod    = (const float*)d_in[7];
  const float* alpha1 = (const float*)d_in[8];
  float* out = (float*)d_out;

  char* p = (char*)d_ws;
  auto take = [&](size_t bytes) {
    char* q = p;
    p += (bytes + 255) & ~(size_t)255;
    return q;
  };
  u16*   xb   = (u16*)  take((size_t)MPAD * NFEAT * 2);
  float* H    = (float*)take((size_t)NHEADS * NN * NHID * 4);
  u16*   Hb   = (u16*)  take((size_t)NHEADS * NN * NHID * 2);
  float* srcv = (float*)take((size_t)NHEADS * NN * 4);
  float* dstv = (float*)take((size_t)NHEADS * NN * 4);
  u16*   eb   = (u16*)  take((size_t)NHEADS * NN * 320 * 2);
  float* rs   = (float*)take((size_t)NHEADS * NN * 4);
  float* h2   = (float*)take((size_t)NN * NHEADS * NHID * 4);
  float* hL2  = (float*)take((size_t)NN * NCLS * 4);
  float* s2   = (float*)take((size_t)NN * 4);
  float* d2   = (float*)take((size_t)NN * 4);
  float* o2   = (float*)take((size_t)NN * NCLS * 4);

  cvt_x<<<640, 256, 0, stream>>>(x, xb);
  gemm1<<<256, 1024, 0, stream>>>(xb, W, H, Hb);
  srcdst<<<dim3(NN, NHEADS), 256, 0, stream>>>(H, a_src, a_dst, srcv, dstv);
  ekern<<<dim3(NN, NHEADS), 320, 0, stream>>>(adj, srcv, dstv, eb, rs);
  gemm2<<<256, 512, 0, stream>>>(eb, Hb, rs, h2);
  layer2<<<NN, 256, 0, stream>>>(h2, W_out, aos, aod, hL2, s2, d2);
  out2k<<<NN, 256, 0, stream>>>(adj, s2, d2, hL2, o2);
  finalk<<<65, 256, 0, stream>>>(o2, alpha1, out);
}

// Round 3
// 139.527 us; speedup vs baseline: 1.5145x; 1.5145x over previous
//
#include <hip/hip_runtime.h>
#include <hip/hip_bf16.h>

#define NN     270
#define MPAD   320
#define NFEAT  4096
#define NHID   1024
#define NHEADS 8
#define NCLS   8
#define NDRUG  175
#define NMIC   95
#define LALPHA 0.2f

typedef unsigned short u16;
typedef unsigned int   u32;
typedef __attribute__((ext_vector_type(8))) short bf16x8;
typedef __attribute__((ext_vector_type(4))) short bf16x4;
typedef __attribute__((ext_vector_type(4))) float f32x4;

static __device__ __forceinline__ u16 f2bf(float f) {
  union { float f; u32 u; } v; v.f = f;
  u32 r = v.u + 0x7FFFu + ((v.u >> 16) & 1u);   // round-to-nearest-even
  return (u16)(r >> 16);
}
static __device__ __forceinline__ float bf2f(u16 b) {
  union { u32 u; float f; } v; v.u = ((u32)b) << 16;
  return v.f;
}
static __device__ __forceinline__ float wave_red(float v) {
  #pragma unroll
  for (int o = 32; o > 0; o >>= 1) v += __shfl_down(v, o, 64);
  return v;
}
// raw barrier with compiler-level memory fence (no vmcnt drain!)
static __device__ __forceinline__ void block_sync() {
  asm volatile("" ::: "memory");
  __builtin_amdgcn_s_barrier();
  asm volatile("" ::: "memory");
}
#define GLOAD16(g, l) __builtin_amdgcn_global_load_lds(                    \
    (__attribute__((address_space(1))) void*)(g),                          \
    (__attribute__((address_space(3))) void*)(l), 16, 0, 0)

// ---------------- K0: x (f32) -> xb (bf16), zero-padded to 320 rows ----------
__global__ void cvt_x(const float* __restrict__ x, u16* __restrict__ xb) {
  int i = (blockIdx.x * 256 + threadIdx.x) * 8;
  if (i >= MPAD * NFEAT) return;
  int row = i >> 12;                 // / NFEAT
  uint4 o = {0, 0, 0, 0};
  if (row < NN) {
    float4 a = *(const float4*)(x + i);
    float4 b = *(const float4*)(x + i + 4);
    o.x = (u32)f2bf(a.x) | ((u32)f2bf(a.y) << 16);
    o.y = (u32)f2bf(a.z) | ((u32)f2bf(a.w) << 16);
    o.z = (u32)f2bf(b.x) | ((u32)f2bf(b.y) << 16);
    o.w = (u32)f2bf(b.z) | ((u32)f2bf(b.w) << 16);
  }
  *(uint4*)(xb + i) = o;
}

// ---------------- K1: H = x @ W (per head), counted-vmcnt pipeline ----------
// 256 thr = 4 waves. Wave w: rows 80w..80w+79 (m-rep 5), all 32 cols (n-rep 2).
// A: global_load_lds, linear dest, source-swizzled (chunk ^= row&7).
// W: global_load_lds f32 linear -> in-LDS transpose+cvt to bf16 [col][k]
//    (swizzled), overlapped with previous tile's MFMAs.
// Raw s_barrier + hand-counted vmcnt: loads stay in flight ~2 iterations.
__global__ __launch_bounds__(256) void gemm1(const u16* __restrict__ xb,
                                             const float* __restrict__ W,
                                             float* __restrict__ H,
                                             u16* __restrict__ Hb) {
  __shared__ __align__(16) u16   lA[2][MPAD * 64];   // 2 x 40 KB, swizzled chunks
  __shared__ __align__(16) float lWf[3][64 * 32];    // 3 x 8 KB, linear [k][col]
  __shared__ __align__(16) u32   lWbf[2][1024];      // 2 x 4 KB, bf16 [col][k] swz
  const int tid  = threadIdx.x;
  const int lane = tid & 63;
  const int wv   = tid >> 6;         // 0..3
  const int c0   = blockIdx.x * 32;
  const int headB = c0 >> 10;
  const int jB    = c0 & 1023;

  // per-thread global staging bases (bytes)
  const char* gA0 = (const char*)xb + (tid >> 3) * 8192
                    + (((tid & 7) ^ ((tid >> 3) & 7)) << 4);       // src swizzle
  const char* gW0 = (const char*)W + (size_t)headB * 16777216 + jB * 4
                    + (tid >> 3) * 4096 + ((tid & 7) << 4);

  auto issueA = [&](int t) {
    char* l0 = (char*)&lA[t & 1][0] + tid * 16;
    const char* g0 = gA0 + t * 128;
    #pragma unroll
    for (int s = 0; s < 10; ++s)
      GLOAD16(g0 + s * 262144, l0 + s * 4096);
  };
  auto issueW = [&](int t) {
    char* l0 = (char*)&lWf[t % 3][0] + tid * 16;
    const char* g0 = gW0 + (size_t)t * 262144;
    GLOAD16(g0, l0);
    GLOAD16(g0 + 131072, l0 + 4096);
  };
  const int tcol = tid & 31;
  const int tk8  = (tid >> 5) << 3;
  auto transposeW = [&](int j) {      // lWf[j%3] (f32 [k][col]) -> lWbf[j&1]
    const float* wf = &lWf[j % 3][0];
    u32* dst = (u32*)((char*)&lWbf[j & 1][0] + tcol * 128
                      + (((tid >> 5) ^ (tid & 7)) << 4));
    #pragma unroll
    for (int q = 0; q < 4; ++q) {
      float f0 = wf[(tk8 + 2 * q    ) * 32 + tcol];
      float f1 = wf[(tk8 + 2 * q + 1) * 32 + tcol];
      dst[q] = (u32)f2bf(f0) | ((u32)f2bf(f1) << 16);
    }
  };

  f32x4 acc[5][2];
  #pragma unroll
  for (int m = 0; m < 5; ++m) {
    acc[m][0] = (f32x4){0.f, 0.f, 0.f, 0.f};
    acc[m][1] = (f32x4){0.f, 0.f, 0.f, 0.f};
  }

  // prologue: FIFO = W0(2) W1(2) A0(10) A1(10) W2(2)  -> 26 outstanding
  issueW(0); issueW(1); issueA(0); issueA(1); issueW(2);
  asm volatile("s_waitcnt vmcnt(24)" ::: "memory");  // W0 landed
  block_sync();                                      // all waves' W0 landed
  transposeW(0);
  asm volatile("s_waitcnt lgkmcnt(0)" ::: "memory");

  for (int i = 0; i < 64; ++i) {
    // steady FIFO at top: [A(i) W(i+1)][A(i+1) W(i+2)] -> wait leaves 12
    if (i <= 61)      asm volatile("s_waitcnt vmcnt(12)" ::: "memory");
    else if (i == 62) asm volatile("s_waitcnt vmcnt(10)" ::: "memory");
    else              asm volatile("s_waitcnt vmcnt(0)"  ::: "memory");
    block_sync();   // barrier1: tile i (A) + tile i+1 (Wf) visible, Wbf(i) published

    {
      const char* aB = (const char*)&lA[i & 1][0];
      const char* bB = (const char*)&lWbf[i & 1][0];
      #pragma unroll
      for (int sub = 0; sub < 2; ++sub) {
        bf16x8 bfr[2];
        #pragma unroll
        for (int n = 0; n < 2; ++n) {
          const int col = n * 16 + (lane & 15);
          const int ch  = (sub * 4 + (lane >> 4)) ^ (col & 7);
          bfr[n] = *(const bf16x8*)(bB + col * 128 + ch * 16);
        }
        #pragma unroll
        for (int m = 0; m < 5; ++m) {
          const int row = wv * 80 + m * 16 + (lane & 15);
          const int ch  = (sub * 4 + (lane >> 4)) ^ (row & 7);
          bf16x8 afr = *(const bf16x8*)(aB + row * 128 + ch * 16);
          acc[m][0] = __builtin_amdgcn_mfma_f32_16x16x32_bf16(afr, bfr[0], acc[m][0], 0, 0, 0);
          acc[m][1] = __builtin_amdgcn_mfma_f32_16x16x32_bf16(afr, bfr[1], acc[m][1], 0, 0, 0);
        }
      }
      if (i < 63) transposeW(i + 1);   // overlap with MFMAs; published at next barrier1
    }
    asm volatile("s_waitcnt lgkmcnt(0)" ::: "memory");
    block_sync();   // barrier2: everyone done reading lA[i&1] / lWf[(i+1)%3]
    if (i <= 61) issueA(i + 2);
    if (i <= 60) issueW(i + 3);
  }

  // epilogue: write H (f32) + Hb (bf16)
  #pragma unroll
  for (int m = 0; m < 5; ++m)
    #pragma unroll
    for (int n = 0; n < 2; ++n)
      #pragma unroll
      for (int r = 0; r < 4; ++r) {
        int row = wv * 80 + m * 16 + ((lane >> 4) << 2) + r;
        if (row < NN) {
          float v = acc[m][n][r];
          int c = c0 + n * 16 + (lane & 15);
          size_t off = ((size_t)headB * NN + row) * NHID + (c & 1023);
          H[off]  = v;
          Hb[off] = f2bf(v);
        }
      }
}

// ---------------- K2: src/dst = H @ a_src / a_dst ----------------
__global__ void srcdst(const float* __restrict__ H, const float* __restrict__ a_src,
                       const float* __restrict__ a_dst, float* __restrict__ srcv,
                       float* __restrict__ dstv) {
  const int i = blockIdx.x, h = blockIdx.y;
  const float* hr = H + ((size_t)h * NN + i) * NHID;
  const float* as = a_src + h * NHID;
  const float* ad = a_dst + h * NHID;
  float s = 0.f, d = 0.f;
  for (int j = threadIdx.x; j < NHID; j += 256) {
    float v = hr[j];
    s += v * as[j];
    d += v * ad[j];
  }
  s = wave_red(s); d = wave_red(d);
  __shared__ float rb[8];
  const int lane = threadIdx.x & 63, wid = threadIdx.x >> 6;
  if (lane == 0) { rb[wid] = s; rb[4 + wid] = d; }
  __syncthreads();
  if (threadIdx.x == 0) {
    srcv[h * NN + i] = rb[0] + rb[1] + rb[2] + rb[3];
    dstv[h * NN + i] = rb[4] + rb[5] + rb[6] + rb[7];
  }
}

// ---------------- K3a: e = exp(-leakyrelu(src_i+dst_j))*mask, rowsum ----------------
__global__ void ekern(const int* __restrict__ adj, const float* __restrict__ srcv,
                      const float* __restrict__ dstv, u16* __restrict__ eb,
                      float* __restrict__ rowsum) {
  const int i = blockIdx.x, h = blockIdx.y;
  const int n = threadIdx.x;          // 0..319
  float ev = 0.f;
  if (n < NN && adj[i * NN + n] != 0) {
    float lg = srcv[h * NN + i] + dstv[h * NN + n];
    float lr = lg > 0.f ? lg : LALPHA * lg;
    ev = expf(-lr);
  }
  u16 evb = f2bf(ev);
  eb[(size_t)h * NN * 320 + (size_t)i * 320 + n] = evb;
  float evr = wave_red(bf2f(evb));    // sum the bf16-rounded weights (consistency)
  __shared__ float rb[5];
  const int lane = threadIdx.x & 63, wid = threadIdx.x >> 6;
  if (lane == 0) rb[wid] = evr;
  __syncthreads();
  if (threadIdx.x == 0) rowsum[h * NN + i] = rb[0] + rb[1] + rb[2] + rb[3] + rb[4];
}

// ---------------- K3b: h2 = elu((e @ H) / rowsum), concat heads ----------------
__global__ __launch_bounds__(512) void gemm2(const u16* __restrict__ eb,
                                             const u16* __restrict__ Hb,
                                             const float* __restrict__ rowsum,
                                             float* __restrict__ h2) {
  __shared__ __align__(16) u16 lA[320 * 72];
  __shared__ __align__(16) u16 lB[32 * 72];
  const int tid  = threadIdx.x;
  const int lane = tid & 63;
  const int wid  = tid >> 6;
  const int wm   = wid >> 1;
  const int wn   = wid & 1;
  const int head = blockIdx.x >> 5;
  const int j0   = (blockIdx.x & 31) * 32;
  f32x4 acc[5];
  #pragma unroll
  for (int m = 0; m < 5; ++m) acc[m] = (f32x4){0.f, 0.f, 0.f, 0.f};

  for (int k0 = 0; k0 < 320; k0 += 64) {
    __syncthreads();
    #pragma unroll
    for (int it = 0; it < 5; ++it) {
      int f   = tid + it * 512;
      int row = f >> 3;
      int kc  = (f & 7) << 3;
      bf16x8 v = {0,0,0,0,0,0,0,0};
      if (row < NN) v = *(const bf16x8*)(eb + (size_t)head * NN * 320 + (size_t)row * 320 + k0 + kc);
      *(bf16x8*)(lA + row * 72 + kc) = v;
    }
    {
      int kk2 = tid >> 3;
      int jc2 = (tid & 7) << 2;
      int k   = k0 + kk2;
      u16 v0 = 0, v1 = 0, v2 = 0, v3 = 0;
      if (k < NN) {
        bf16x4 hv = *(const bf16x4*)(Hb + (size_t)head * NN * NHID + (size_t)k * NHID + j0 + jc2);
        v0 = (u16)hv[0]; v1 = (u16)hv[1]; v2 = (u16)hv[2]; v3 = (u16)hv[3];
      }
      lB[(jc2 + 0) * 72 + kk2] = v0;
      lB[(jc2 + 1) * 72 + kk2] = v1;
      lB[(jc2 + 2) * 72 + kk2] = v2;
      lB[(jc2 + 3) * 72 + kk2] = v3;
    }
    __syncthreads();
    #pragma unroll
    for (int sub = 0; sub < 2; ++sub) {
      int ks = sub * 32 + ((lane >> 4) << 3);
      bf16x8 bfrag = *(const bf16x8*)(lB + (wn * 16 + (lane & 15)) * 72 + ks);
      #pragma unroll
      for (int m = 0; m < 5; ++m) {
        int row = wm * 80 + m * 16 + (lane & 15);
        bf16x8 afrag = *(const bf16x8*)(lA + row * 72 + ks);
        acc[m] = __builtin_amdgcn_mfma_f32_16x16x32_bf16(afrag, bfrag, acc[m], 0, 0, 0);
      }
    }
  }
  const int jj = j0 + wn * 16 + (lane & 15);
  #pragma unroll
  for (int m = 0; m < 5; ++m) {
    #pragma unroll
    for (int r = 0; r < 4; ++r) {
      int row = wm * 80 + m * 16 + ((lane >> 4) << 2) + r;
      if (row < NN) {
        float v = acc[m][r] / rowsum[head * NN + row];
        v = v > 0.f ? v : expm1f(v);                 // elu
        h2[(size_t)row * (NHEADS * NHID) + head * NHID + jj] = v;
      }
    }
  }
}

// ---------------- K4: layer-2 h = h2 @ W_out, plus src2/dst2 ----------------
__global__ void layer2(const float* __restrict__ h2, const float* __restrict__ Wout,
                       const float* __restrict__ aos, const float* __restrict__ aod,
                       float* __restrict__ hL2, float* __restrict__ src2,
                       float* __restrict__ dst2) {
  const int i = blockIdx.x;
  float acc[8] = {0,0,0,0,0,0,0,0};
  for (int k = threadIdx.x; k < NHEADS * NHID; k += 256) {
    float hv = h2[(size_t)i * (NHEADS * NHID) + k];
    const float4 w0 = *(const float4*)(Wout + (size_t)k * 8);
    const float4 w1 = *(const float4*)(Wout + (size_t)k * 8 + 4);
    acc[0] += hv * w0.x; acc[1] += hv * w0.y; acc[2] += hv * w0.z; acc[3] += hv * w0.w;
    acc[4] += hv * w1.x; acc[5] += hv * w1.y; acc[6] += hv * w1.z; acc[7] += hv * w1.w;
  }
  #pragma unroll
  for (int c = 0; c < 8; ++c) acc[c] = wave_red(acc[c]);
  __shared__ float rb[4][8];
  const int lane = threadIdx.x & 63, wid = threadIdx.x >> 6;
  if (lane == 0) {
    #pragma unroll
    for (int c = 0; c < 8; ++c) rb[wid][c] = acc[c];
  }
  __syncthreads();
  if (threadIdx.x == 0) {
    float s = 0.f, d = 0.f;
    #pragma unroll
    for (int c = 0; c < 8; ++c) {
      float v = rb[0][c] + rb[1][c] + rb[2][c] + rb[3][c];
      hL2[i * 8 + c] = v;
      s += v * aos[c];
      d += v * aod[c];
    }
    src2[i] = s; dst2[i] = d;
  }
}

// ---------------- K5a: layer-2 attention + aggregation + elu ----------------
__global__ void out2k(const int* __restrict__ adj, const float* __restrict__ src2,
                      const float* __restrict__ dst2, const float* __restrict__ hL2,
                      float* __restrict__ out2) {
  const int i = blockIdx.x;
  float se = 0.f, acc[8] = {0,0,0,0,0,0,0,0};
  for (int n = threadIdx.x; n < NN; n += 256) {
    if (adj[i * NN + n] != 0) {
      float lg = src2[i] + dst2[n];
      float lr = lg > 0.f ? lg : LALPHA * lg;
      float ev = expf(-lr);
      se += ev;
      #pragma unroll
      for (int c = 0; c < 8; ++c) acc[c] += ev * hL2[n * 8 + c];
    }
  }
  se = wave_red(se);
  #pragma unroll
  for (int c = 0; c < 8; ++c) acc[c] = wave_red(acc[c]);
  __shared__ float rb[4][9];
  const int lane = threadIdx.x & 63, wid = threadIdx.x >> 6;
  if (lane == 0) {
    #pragma unroll
    for (int c = 0; c < 8; ++c) rb[wid][c] = acc[c];
    rb[wid][8] = se;
  }
  __syncthreads();
  if (threadIdx.x == 0) {
    float s = rb[0][8] + rb[1][8] + rb[2][8] + rb[3][8];
    #pragma unroll
    for (int c = 0; c < 8; ++c) {
      float v = (rb[0][c] + rb[1][c] + rb[2][c] + rb[3][c]) / s;
      out2[i * 8 + c] = v > 0.f ? v : expm1f(v);
    }
  }
}

// ---------------- K5b: out = drug @ alpha1 @ mic^T ----------------
__global__ void finalk(const float* __restrict__ out2, const float* __restrict__ alpha1,
                       float* __restrict__ out) {
  int t = blockIdx.x * 256 + threadIdx.x;
  if (t >= NDRUG * NMIC) return;
  int d = t / NMIC, m = t % NMIC;
  const float* dr = out2 + d * 8;
  const float* mi = out2 + (NDRUG + m) * 8;
  float r = 0.f;
  #pragma unroll
  for (int c2 = 0; c2 < 8; ++c2) {
    float a = 0.f;
    #pragma unroll
    for (int c1 = 0; c1 < 8; ++c1) a += dr[c1] * alpha1[c1 * 8 + c2];
    r += a * mi[c2];
  }
  out[t] = r;
}

extern "C" void kernel_launch(void* const* d_in, const int* in_sizes, int n_in,
                              void* d_out, int out_size, void* d_ws, size_t ws_size,
                              hipStream_t stream) {
  const float* x      = (const float*)d_in[0];
  const int*   adj    = (const int*)d_in[1];
  const float* W      = (const float*)d_in[2];
  const float* a_src  = (const float*)d_in[3];
  const float* a_dst  = (const float*)d_in[4];
  const float* W_out  = (const float*)d_in[5];
  const float* aos    = (const float*)d_in[6];
  const float* aod    = (const float*)d_in[7];
  const float* alpha1 = (const float*)d_in[8];
  float* out = (float*)d_out;

  char* p = (char*)d_ws;
  auto take = [&](size_t bytes) {
    char* q = p;
    p += (bytes + 255) & ~(size_t)255;
    return q;
  };
  u16*   xb   = (u16*)  take((size_t)MPAD * NFEAT * 2);
  float* H    = (float*)take((size_t)NHEADS * NN * NHID * 4);
  u16*   Hb   = (u16*)  take((size_t)NHEADS * NN * NHID * 2);
  float* srcv = (float*)take((size_t)NHEADS * NN * 4);
  float* dstv = (float*)take((size_t)NHEADS * NN * 4);
  u16*   eb   = (u16*)  take((size_t)NHEADS * NN * 320 * 2);
  float* rs   = (float*)take((size_t)NHEADS * NN * 4);
  float* h2   = (float*)take((size_t)NN * NHEADS * NHID * 4);
  float* hL2  = (float*)take((size_t)NN * NCLS * 4);
  float* s2   = (float*)take((size_t)NN * 4);
  float* d2   = (float*)take((size_t)NN * 4);
  float* o2   = (float*)take((size_t)NN * NCLS * 4);

  cvt_x<<<640, 256, 0, stream>>>(x, xb);
  gemm1<<<256, 256, 0, stream>>>(xb, W, H, Hb);
  srcdst<<<dim3(NN, NHEADS), 256, 0, stream>>>(H, a_src, a_dst, srcv, dstv);
  ekern<<<dim3(NN, NHEADS), 320, 0, stream>>>(adj, srcv, dstv, eb, rs);
  gemm2<<<256, 512, 0, stream>>>(eb, Hb, rs, h2);
  layer2<<<NN, 256, 0, stream>>>(h2, W_out, aos, aod, hL2, s2, d2);
  out2k<<<NN, 256, 0, stream>>>(adj, s2, d2, hL2, o2);
  finalk<<<65, 256, 0, stream>>>(o2, alpha1, out);
}

// Round 5
// 91.771 us; speedup vs baseline: 2.3027x; 1.5204x over previous
//
#include <hip/hip_runtime.h>
#include <hip/hip_bf16.h>

#define NN     270
#define MPAD   320
#define NFEAT  4096
#define NHID   1024
#define NHEADS 8
#define NCLS   8
#define NDRUG  175
#define NMIC   95
#define LALPHA 0.2f

typedef unsigned short u16;
typedef unsigned int   u32;
typedef __attribute__((ext_vector_type(8))) short bf16x8;
typedef __attribute__((ext_vector_type(4))) short bf16x4;
typedef __attribute__((ext_vector_type(4))) float f32x4;

static __device__ __forceinline__ u16 f2bf(float f) {
  union { float f; u32 u; } v; v.f = f;
  u32 r = v.u + 0x7FFFu + ((v.u >> 16) & 1u);   // round-to-nearest-even
  return (u16)(r >> 16);
}
static __device__ __forceinline__ float bf2f(u16 b) {
  union { u32 u; float f; } v; v.u = ((u32)b) << 16;
  return v.f;
}
static __device__ __forceinline__ float wave_red(float v) {
  #pragma unroll
  for (int o = 32; o > 0; o >>= 1) v += __shfl_down(v, o, 64);
  return v;
}
// raw barrier with compiler-level memory fence (no vmcnt drain!)
static __device__ __forceinline__ void block_sync() {
  asm volatile("" ::: "memory");
  __builtin_amdgcn_s_barrier();
  asm volatile("" ::: "memory");
}
#define GLOAD16(g, l) __builtin_amdgcn_global_load_lds(                    \
    (__attribute__((address_space(1))) void*)(g),                          \
    (__attribute__((address_space(3))) void*)(l), 16, 0, 0)

// ---------------- K0: x (f32) -> xb (bf16), zero-padded to 320 rows ----------
__global__ void cvt_x(const float* __restrict__ x, u16* __restrict__ xb) {
  int i = (blockIdx.x * 256 + threadIdx.x) * 8;
  if (i >= MPAD * NFEAT) return;
  int row = i >> 12;                 // / NFEAT
  uint4 o = {0, 0, 0, 0};
  if (row < NN) {
    float4 a = *(const float4*)(x + i);
    float4 b = *(const float4*)(x + i + 4);
    o.x = (u32)f2bf(a.x) | ((u32)f2bf(a.y) << 16);
    o.y = (u32)f2bf(a.z) | ((u32)f2bf(a.w) << 16);
    o.z = (u32)f2bf(b.x) | ((u32)f2bf(b.y) << 16);
    o.w = (u32)f2bf(b.z) | ((u32)f2bf(b.w) << 16);
  }
  *(uint4*)(xb + i) = o;
}

// ---------------- K1: Hpart[ks] = x @ W[kchunk ks] (per head), bf16 partials --
// 512 blocks = 128 n-tiles (64 cols) x 4 K-chunks (K=1024) -> 2 blocks/CU (72KB LDS).
// 256 thr = 4 waves; wave w: rows 80w..80w+79 (m-rep 5), all 64 cols (n-rep 4).
// A: global_load_lds (linear dest, source chunk-swizzled g = p ^ ((r>>1)&3)).
//    NOTE ks offset is ks*1024 ELEMENTS = ks*2048 BYTES (r4 bug: was ks*4096).
// W: global_load_lds f32 [k][col] -> in-LDS transpose+cvt to bf16 [kb][col] 16B
//    chunks (conflict-free for b128), overlapped with previous tile's MFMAs.
// Counted vmcnt: A 2-deep, W 3-deep; steady wait leaves 7 in flight.
__global__ __launch_bounds__(256, 2) void gemm1(const u16* __restrict__ xb,
                                                const float* __restrict__ W,
                                                u16* __restrict__ Hpart) {
  __shared__ __align__(16) u16   lA[2][MPAD * 32];   // 2 x 20 KB  [row][32k] swz chunks
  __shared__ __align__(16) float lWf[3][32 * 64];    // 3 x 8 KB   [k][col] linear
  __shared__ __align__(16) u32   lWbf[2][1024];      // 2 x 4 KB   [kb][col][16B]
  const int tid  = threadIdx.x;
  const int lane = tid & 63;
  const int wv   = tid >> 6;         // 0..3
  const int b    = blockIdx.x;
  const int ntile = b >> 2;          // 0..127
  const int ks    = b & 3;           // K-chunk
  const int head  = ntile >> 4;
  const int jB    = (ntile & 15) * 64;

  // per-thread global staging bases (bytes)
  const char* gA0 = (const char*)xb + (tid >> 2) * 8192 + ks * 2048
                    + (((tid & 3) ^ ((tid >> 3) & 3)) << 4);       // src swizzle
  const char* gW0 = (const char*)W + (size_t)head * 16777216 + (size_t)ks * 4194304
                    + (tid >> 4) * 4096 + jB * 4 + ((tid & 15) << 4);

  auto issueA = [&](int j) {
    char* l0 = (char*)&lA[j & 1][0] + tid * 16;
    const char* g0 = gA0 + j * 64;
    #pragma unroll
    for (int s = 0; s < 5; ++s)
      GLOAD16(g0 + s * 524288, l0 + s * 4096);
  };
  auto issueW = [&](int j) {
    char* l0 = (char*)&lWf[j % 3][0] + tid * 16;
    const char* g0 = gW0 + j * 131072;
    GLOAD16(g0, l0);
    GLOAD16(g0 + 65536, l0 + 4096);
  };
  const int tcol = tid & 63;
  const int tkb  = tid >> 6;
  auto transposeW = [&](int j) {      // lWf[j%3] f32 [k][col] -> lWbf[j&1] bf16
    const float* wf = &lWf[j % 3][0];
    float f[8];
    #pragma unroll
    for (int q = 0; q < 8; ++q) f[q] = wf[(tkb * 8 + q) * 64 + tcol];
    uint4 o;
    o.x = (u32)f2bf(f[0]) | ((u32)f2bf(f[1]) << 16);
    o.y = (u32)f2bf(f[2]) | ((u32)f2bf(f[3]) << 16);
    o.z = (u32)f2bf(f[4]) | ((u32)f2bf(f[5]) << 16);
    o.w = (u32)f2bf(f[6]) | ((u32)f2bf(f[7]) << 16);
    *(uint4*)((char*)&lWbf[j & 1][0] + tkb * 1024 + tcol * 16) = o;
  };

  f32x4 acc[5][4];
  #pragma unroll
  for (int m = 0; m < 5; ++m)
    #pragma unroll
    for (int n = 0; n < 4; ++n) acc[m][n] = (f32x4){0.f, 0.f, 0.f, 0.f};

  // prologue FIFO: W0(2) W1(2) A0(5) A1(5) W2(2) = 16 outstanding
  issueW(0); issueW(1); issueA(0); issueA(1); issueW(2);
  asm volatile("s_waitcnt vmcnt(14)" ::: "memory");  // W0 landed
  block_sync();
  transposeW(0);
  asm volatile("s_waitcnt lgkmcnt(0)" ::: "memory");

  const int lc = lane & 15;
  const int lg = lane >> 4;
  for (int j = 0; j < 32; ++j) {
    // steady outstanding at top: [A(j):5, W(j+1):2, A(j+1):5, W(j+2):2] = 14
    if (j <= 29)      asm volatile("s_waitcnt vmcnt(7)" ::: "memory");
    else if (j == 30) asm volatile("s_waitcnt vmcnt(5)" ::: "memory");
    else              asm volatile("s_waitcnt vmcnt(0)" ::: "memory");
    block_sync();   // barrier1: A(j), W(j+1) visible; Wbf(j) published

    {
      const char* aB = (const char*)&lA[j & 1][0];
      const char* bB = (const char*)&lWbf[j & 1][0];
      bf16x8 bfr[4];
      #pragma unroll
      for (int n = 0; n < 4; ++n)
        bfr[n] = *(const bf16x8*)(bB + lg * 1024 + (n * 16 + lc) * 16);
      #pragma unroll
      for (int m = 0; m < 5; ++m) {
        const int row = wv * 80 + m * 16 + lc;
        bf16x8 afr = *(const bf16x8*)(aB + row * 64 + ((lg ^ ((row >> 1) & 3)) << 4));
        #pragma unroll
        for (int n = 0; n < 4; ++n)
          acc[m][n] = __builtin_amdgcn_mfma_f32_16x16x32_bf16(afr, bfr[n], acc[m][n], 0, 0, 0);
      }
      if (j < 31) transposeW(j + 1);   // overlaps MFMAs; published at next barrier1
    }
    asm volatile("s_waitcnt lgkmcnt(0)" ::: "memory");
    block_sync();   // barrier2: lA[j&1] / lWf[(j+3)%3] free for refill
    if (j <= 29) issueA(j + 2);
    if (j <= 28) issueW(j + 3);
  }

  // epilogue: bf16 partials
  u16* hp = Hpart + (size_t)ks * (NN * 8192) + (size_t)(ntile * 64);
  #pragma unroll
  for (int m = 0; m < 5; ++m)
    #pragma unroll
    for (int r = 0; r < 4; ++r) {
      const int row = wv * 80 + m * 16 + (lg << 2) + r;
      if (row < NN) {
        #pragma unroll
        for (int n = 0; n < 4; ++n)
          hp[(size_t)row * 8192 + n * 16 + lc] = f2bf(acc[m][n][r]);
      }
    }
}

// ---------------- K2: reduce K-partials + src/dst dots + Hb (bf16) ----------
__global__ void srcdstf(const u16* __restrict__ Hp, const float* __restrict__ a_src,
                        const float* __restrict__ a_dst, u16* __restrict__ Hb,
                        float* __restrict__ srcv, float* __restrict__ dstv) {
  const int i = blockIdx.x, h = blockIdx.y;
  const int tid = threadIdx.x;
  const int j4 = tid * 4;
  const u16* base = Hp + (size_t)i * 8192 + h * 1024 + j4;
  float4 v = {0.f, 0.f, 0.f, 0.f};
  #pragma unroll
  for (int q = 0; q < 4; ++q) {
    bf16x4 p = *(const bf16x4*)(base + (size_t)q * (NN * 8192));
    v.x += bf2f((u16)p[0]); v.y += bf2f((u16)p[1]);
    v.z += bf2f((u16)p[2]); v.w += bf2f((u16)p[3]);
  }
  // Hb
  u16* hb = Hb + ((size_t)h * NN + i) * NHID + j4;
  ushort4 hv = { f2bf(v.x), f2bf(v.y), f2bf(v.z), f2bf(v.w) };
  *(ushort4*)hb = hv;
  // dots
  const float4 as4 = *(const float4*)(a_src + h * NHID + j4);
  const float4 ad4 = *(const float4*)(a_dst + h * NHID + j4);
  float s = v.x * as4.x + v.y * as4.y + v.z * as4.z + v.w * as4.w;
  float d = v.x * ad4.x + v.y * ad4.y + v.z * ad4.z + v.w * ad4.w;
  s = wave_red(s); d = wave_red(d);
  __shared__ float rb[8];
  const int lane = tid & 63, wid = tid >> 6;
  if (lane == 0) { rb[wid] = s; rb[4 + wid] = d; }
  __syncthreads();
  if (tid == 0) {
    srcv[h * NN + i] = rb[0] + rb[1] + rb[2] + rb[3];
    dstv[h * NN + i] = rb[4] + rb[5] + rb[6] + rb[7];
  }
}

// ---------------- K3a: e = exp(-leakyrelu(src_i+dst_j))*mask, rowsum ----------------
__global__ void ekern(const int* __restrict__ adj, const float* __restrict__ srcv,
                      const float* __restrict__ dstv, u16* __restrict__ eb,
                      float* __restrict__ rowsum) {
  const int i = blockIdx.x, h = blockIdx.y;
  const int n = threadIdx.x;          // 0..319
  float ev = 0.f;
  if (n < NN && adj[i * NN + n] != 0) {
    float lg = srcv[h * NN + i] + dstv[h * NN + n];
    float lr = lg > 0.f ? lg : LALPHA * lg;
    ev = expf(-lr);
  }
  u16 evb = f2bf(ev);
  eb[(size_t)h * NN * 320 + (size_t)i * 320 + n] = evb;
  float evr = wave_red(bf2f(evb));    // sum the bf16-rounded weights (consistency)
  __shared__ float rb[5];
  const int lane = threadIdx.x & 63, wid = threadIdx.x >> 6;
  if (lane == 0) rb[wid] = evr;
  __syncthreads();
  if (threadIdx.x == 0) rowsum[h * NN + i] = rb[0] + rb[1] + rb[2] + rb[3] + rb[4];
}

// ---------------- K3b: h2 = elu((e @ H) / rowsum), concat heads ----------------
__global__ __launch_bounds__(512) void gemm2(const u16* __restrict__ eb,
                                             const u16* __restrict__ Hb,
                                             const float* __restrict__ rowsum,
                                             float* __restrict__ h2) {
  __shared__ __align__(16) u16 lA[320 * 72];
  __shared__ __align__(16) u16 lB[32 * 72];
  const int tid  = threadIdx.x;
  const int lane = tid & 63;
  const int wid  = tid >> 6;
  const int wm   = wid >> 1;
  const int wn   = wid & 1;
  const int head = blockIdx.x >> 5;
  const int j0   = (blockIdx.x & 31) * 32;
  f32x4 acc[5];
  #pragma unroll
  for (int m = 0; m < 5; ++m) acc[m] = (f32x4){0.f, 0.f, 0.f, 0.f};

  for (int k0 = 0; k0 < 320; k0 += 64) {
    __syncthreads();
    #pragma unroll
    for (int it = 0; it < 5; ++it) {
      int f   = tid + it * 512;
      int row = f >> 3;
      int kc  = (f & 7) << 3;
      bf16x8 v = {0,0,0,0,0,0,0,0};
      if (row < NN) v = *(const bf16x8*)(eb + (size_t)head * NN * 320 + (size_t)row * 320 + k0 + kc);
      *(bf16x8*)(lA + row * 72 + kc) = v;
    }
    {
      int kk2 = tid >> 3;
      int jc2 = (tid & 7) << 2;
      int k   = k0 + kk2;
      u16 v0 = 0, v1 = 0, v2 = 0, v3 = 0;
      if (k < NN) {
        bf16x4 hv = *(const bf16x4*)(Hb + (size_t)head * NN * NHID + (size_t)k * NHID + j0 + jc2);
        v0 = (u16)hv[0]; v1 = (u16)hv[1]; v2 = (u16)hv[2]; v3 = (u16)hv[3];
      }
      lB[(jc2 + 0) * 72 + kk2] = v0;
      lB[(jc2 + 1) * 72 + kk2] = v1;
      lB[(jc2 + 2) * 72 + kk2] = v2;
      lB[(jc2 + 3) * 72 + kk2] = v3;
    }
    __syncthreads();
    #pragma unroll
    for (int sub = 0; sub < 2; ++sub) {
      int ksub = sub * 32 + ((lane >> 4) << 3);
      bf16x8 bfrag = *(const bf16x8*)(lB + (wn * 16 + (lane & 15)) * 72 + ksub);
      #pragma unroll
      for (int m = 0; m < 5; ++m) {
        int row = wm * 80 + m * 16 + (lane & 15);
        bf16x8 afrag = *(const bf16x8*)(lA + row * 72 + ksub);
        acc[m] = __builtin_amdgcn_mfma_f32_16x16x32_bf16(afrag, bfrag, acc[m], 0, 0, 0);
      }
    }
  }
  const int jj = j0 + wn * 16 + (lane & 15);
  #pragma unroll
  for (int m = 0; m < 5; ++m) {
    #pragma unroll
    for (int r = 0; r < 4; ++r) {
      int row = wm * 80 + m * 16 + ((lane >> 4) << 2) + r;
      if (row < NN) {
        float v = acc[m][r] / rowsum[head * NN + row];
        v = v > 0.f ? v : expm1f(v);                 // elu
        h2[(size_t)row * (NHEADS * NHID) + head * NHID + jj] = v;
      }
    }
  }
}

// ---------------- K4: layer-2 h = h2 @ W_out, plus src2/dst2 ----------------
__global__ void layer2(const float* __restrict__ h2, const float* __restrict__ Wout,
                       const float* __restrict__ aos, const float* __restrict__ aod,
                       float* __restrict__ hL2, float* __restrict__ src2,
                       float* __restrict__ dst2) {
  const int i = blockIdx.x;
  float acc[8] = {0,0,0,0,0,0,0,0};
  for (int k = threadIdx.x; k < NHEADS * NHID; k += 256) {
    float hv = h2[(size_t)i * (NHEADS * NHID) + k];
    const float4 w0 = *(const float4*)(Wout + (size_t)k * 8);
    const float4 w1 = *(const float4*)(Wout + (size_t)k * 8 + 4);
    acc[0] += hv * w0.x; acc[1] += hv * w0.y; acc[2] += hv * w0.z; acc[3] += hv * w0.w;
    acc[4] += hv * w1.x; acc[5] += hv * w1.y; acc[6] += hv * w1.z; acc[7] += hv * w1.w;
  }
  #pragma unroll
  for (int c = 0; c < 8; ++c) acc[c] = wave_red(acc[c]);
  __shared__ float rb[4][8];
  const int lane = threadIdx.x & 63, wid = threadIdx.x >> 6;
  if (lane == 0) {
    #pragma unroll
    for (int c = 0; c < 8; ++c) rb[wid][c] = acc[c];
  }
  __syncthreads();
  if (threadIdx.x == 0) {
    float s = 0.f, d = 0.f;
    #pragma unroll
    for (int c = 0; c < 8; ++c) {
      float v = rb[0][c] + rb[1][c] + rb[2][c] + rb[3][c];
      hL2[i * 8 + c] = v;
      s += v * aos[c];
      d += v * aod[c];
    }
    src2[i] = s; dst2[i] = d;
  }
}

// ---------------- K5a: layer-2 attention + aggregation + elu ----------------
__global__ void out2k(const int* __restrict__ adj, const float* __restrict__ src2,
                      const float* __restrict__ dst2, const float* __restrict__ hL2,
                      float* __restrict__ out2) {
  const int i = blockIdx.x;
  float se = 0.f, acc[8] = {0,0,0,0,0,0,0,0};
  for (int n = threadIdx.x; n < NN; n += 256) {
    if (adj[i * NN + n] != 0) {
      float lg = src2[i] + dst2[n];
      float lr = lg > 0.f ? lg : LALPHA * lg;
      float ev = expf(-lr);
      se += ev;
      #pragma unroll
      for (int c = 0; c < 8; ++c) acc[c] += ev * hL2[n * 8 + c];
    }
  }
  se = wave_red(se);
  #pragma unroll
  for (int c = 0; c < 8; ++c) acc[c] = wave_red(acc[c]);
  __shared__ float rb[4][9];
  const int lane = threadIdx.x & 63, wid = threadIdx.x >> 6;
  if (lane == 0) {
    #pragma unroll
    for (int c = 0; c < 8; ++c) rb[wid][c] = acc[c];
    rb[wid][8] = se;
  }
  __syncthreads();
  if (threadIdx.x == 0) {
    float s = rb[0][8] + rb[1][8] + rb[2][8] + rb[3][8];
    #pragma unroll
    for (int c = 0; c < 8; ++c) {
      float v = (rb[0][c] + rb[1][c] + rb[2][c] + rb[3][c]) / s;
      out2[i * 8 + c] = v > 0.f ? v : expm1f(v);
    }
  }
}

// ---------------- K5b: out = drug @ alpha1 @ mic^T ----------------
__global__ void finalk(const float* __restrict__ out2, const float* __restrict__ alpha1,
                       float* __restrict__ out) {
  int t = blockIdx.x * 256 + threadIdx.x;
  if (t >= NDRUG * NMIC) return;
  int d = t / NMIC, m = t % NMIC;
  const float* dr = out2 + d * 8;
  const float* mi = out2 + (NDRUG + m) * 8;
  float r = 0.f;
  #pragma unroll
  for (int c2 = 0; c2 < 8; ++c2) {
    float a = 0.f;
    #pragma unroll
    for (int c1 = 0; c1 < 8; ++c1) a += dr[c1] * alpha1[c1 * 8 + c2];
    r += a * mi[c2];
  }
  out[t] = r;
}

extern "C" void kernel_launch(void* const* d_in, const int* in_sizes, int n_in,
                              void* d_out, int out_size, void* d_ws, size_t ws_size,
                              hipStream_t stream) {
  const float* x      = (const float*)d_in[0];
  const int*   adj    = (const int*)d_in[1];
  const float* W      = (const float*)d_in[2];
  const float* a_src  = (const float*)d_in[3];
  const float* a_dst  = (const float*)d_in[4];
  const float* W_out  = (const float*)d_in[5];
  const float* aos    = (const float*)d_in[6];
  const float* aod    = (const float*)d_in[7];
  const float* alpha1 = (const float*)d_in[8];
  float* out = (float*)d_out;

  char* p = (char*)d_ws;
  auto take = [&](size_t bytes) {
    char* q = p;
    p += (bytes + 255) & ~(size_t)255;
    return q;
  };
  u16*   xb    = (u16*)  take((size_t)MPAD * NFEAT * 2);            // 2.62 MB
  u16*   Hpart = (u16*)  take((size_t)4 * NN * 8192 * 2);           // 17.7 MB (bf16 partials)
  u16*   Hb    = (u16*)  take((size_t)NHEADS * NN * NHID * 2);      // 4.42 MB
  float* srcv  = (float*)take((size_t)NHEADS * NN * 4);
  float* dstv  = (float*)take((size_t)NHEADS * NN * 4);
  // --- aliases into Hpart (dead after srcdstf) ---
  char*  hbase = (char*)Hpart;
  float* h2    = (float*)hbase;                                     // 8.85 MB @ +0
  u16*   eb    = (u16*)  (hbase + 10000000);                        // 1.38 MB
  float* rs    = (float*)(hbase + 11500000);
  float* hL2   = (float*)(hbase + 11600000);
  float* s2    = (float*)(hbase + 11700000);
  float* d2    = (float*)(hbase + 11800000);
  float* o2    = (float*)(hbase + 11900000);

  cvt_x<<<640, 256, 0, stream>>>(x, xb);
  gemm1<<<512, 256, 0, stream>>>(xb, W, Hpart);
  srcdstf<<<dim3(NN, NHEADS), 256, 0, stream>>>(Hpart, a_src, a_dst, Hb, srcv, dstv);
  ekern<<<dim3(NN, NHEADS), 320, 0, stream>>>(adj, srcv, dstv, eb, rs);
  gemm2<<<256, 512, 0, stream>>>(eb, Hb, rs, h2);
  layer2<<<NN, 256, 0, stream>>>(h2, W_out, aos, aod, hL2, s2, d2);
  out2k<<<NN, 256, 0, stream>>>(adj, s2, d2, hL2, o2);
  finalk<<<65, 256, 0, stream>>>(o2, alpha1, out);
}